// Round 4
// baseline (3382.360 us; speedup 1.0000x reference)
//
#include <hip/hip_runtime.h>
#include <cstdint>

// ---- problem constants ----
#define NT  4
#define NB  32
#define NC  512
#define NCH 2048
#define NN  196
#define NM  (NB * NN)   // 6272 columns = 98*64
#define NH  8

struct GP {
    const float *q_bn_s, *q_bn_b, *k_bn_s, *k_bn_b;
    const float *proj_b, *proj_bn_s, *proj_bn_b;
    const float *mlp1_b, *mlp1_bn_s, *mlp1_bn_b;
    const float *mlp2_b, *mlp2_bn_s, *mlp2_bn_b;
    const float *wqkT, *wprojT, *wmlp1T, *wmlp2T;  // [K][O] transposed weights
    const float *xT;                                // [T][C][M] permuted input
    float *xy;                                      // [C][M] x + y_spike (per t)
    float *v_q, *v_k, *v_y, *v_h1, *v_h2, *v_attn;  // LIF states, [C][M]
    unsigned char *q_sp, *k_sp, *x_one, *h1_sp, *attn_sp; // binary spikes
    float *out;
    int t;
};

// Exact-f32 LIF step (bitwise-validated vs reference in R2/R3).
__device__ __forceinline__ float lif_step(float z, float v_old, float vth, int& sp) {
    float d = __fsub_rn(z, v_old);
    float h = __fmul_rn(d, 0.5f);
    float v = __fadd_rn(v_old, h);
    sp = (v >= vth) ? 1 : 0;
    return sp ? 0.0f : v;
}

typedef const void __attribute__((address_space(1))) gas_t;
typedef void __attribute__((address_space(3))) las_t;
__device__ __forceinline__ void gl_lds16(const float* g, float* l) {
    // lane i: 16B from g(per-lane addr) -> ldsbase + i*16 (wave-uniform base)
    __builtin_amdgcn_global_load_lds((gas_t*)g, (las_t*)l, 16, 0, 0);
}

// ---------------- pre-kernels ----------------

// dst[c*ldD + offD + o] = src[o*K + c]   (32x32 LDS tiles)
__global__ __launch_bounds__(256) void trw_k(const float* __restrict__ src,
                                             float* __restrict__ dst,
                                             int K, int ldD, int offD) {
    __shared__ float tle[32][33];
    const int c0 = blockIdx.x * 32, o0 = blockIdx.y * 32;
    const int tx = threadIdx.x & 31, ty = threadIdx.x >> 5;  // ty: 0..7
#pragma unroll
    for (int r = 0; r < 4; ++r)
        tle[ty + r * 8][tx] = src[(size_t)(o0 + ty + r * 8) * K + c0 + tx];
    __syncthreads();
#pragma unroll
    for (int r = 0; r < 4; ++r)
        dst[(size_t)(c0 + ty + r * 8) * ldD + offD + o0 + tx] = tle[tx][ty + r * 8];
}

// xT[t][c][b][n] = x[t][b][c][n]
__global__ __launch_bounds__(64) void permx_k(const float* __restrict__ x,
                                              float* __restrict__ xT) {
    const int id = blockIdx.x;         // t*16384 + c*32 + b
    const int b = id & 31;
    const int c = (id >> 5) & 511;
    const int t = id >> 14;
    const float* s = x + ((size_t)(t * NB + b) * NC + c) * NN;
    float* d = xT + ((size_t)(t * NC + c) * NB + b) * NN;
    for (int n = threadIdx.x; n < NN; n += 64) d[n] = s[n];
}

// attn LIF: per (h,m): integer sum of 64 q-spike bytes; LIF vth=0.5
__global__ __launch_bounds__(256) void attn_k(GP gp) {
    const int m = blockIdx.x * 256 + threadIdx.x;
    const int h = blockIdx.y;
    if (m >= NM) return;
    const unsigned char* q = gp.q_sp + (size_t)h * 64 * NM + m;
    int s = 0;
#pragma unroll 8
    for (int d = 0; d < 64; ++d) s += q[(size_t)d * NM];
    float v = gp.t ? gp.v_attn[(size_t)h * NM + m] : 0.0f;
    int sp;
    v = lif_step((float)s, v, 0.5f, sp);
    gp.v_attn[(size_t)h * NM + m] = v;
    gp.attn_sp[(size_t)h * NM + m] = (unsigned char)sp;
}

// x_one = k_sp AND attn_sp  (binary product, exact)
__global__ __launch_bounds__(256) void xone_k(GP gp) {
    const int c = blockIdx.y;
    const int m4 = (blockIdx.x * 256 + threadIdx.x) * 4;
    if (m4 >= NM) return;
    const unsigned int kv = *(const unsigned int*)(gp.k_sp + (size_t)c * NM + m4);
    const unsigned int av = *(const unsigned int*)(gp.attn_sp + (size_t)(c >> 6) * NM + m4);
    *(unsigned int*)(gp.x_one + (size_t)c * NM + m4) = kv & av;
}

// ---------------- fused GEMM + BN + LIF ----------------
// All modes: 256 threads (4 waves), 64o x 64n block tile, per-thread 4x4.
// Double-buffered LDS, one __syncthreads per K-step (m97 pattern).
// MODE 0: q&k stacked (O=1024,K=512), X=xT[t]           unfused mul+add
// MODE 1: proj (O=512,K=512), X=x_one (binary u8)       fma (exact product)
// MODE 2: mlp1 (O=2048,K=512), X=xy                     unfused mul+add
// MODE 3: mlp2 (O=512,K=2048), X=h1_sp (binary u8)      fma; writes out
template <int MODE>
__global__ __launch_bounds__(256) void gemm_lif(GP gp) {
    constexpr bool FUSED = (MODE == 1 || MODE == 3);
    constexpr int K_TOT = (MODE == 3) ? 2048 : 512;
    constexpr int LDA = (MODE == 0) ? 1024 : (MODE == 2) ? 2048 : 512;
    constexpr int BK = FUSED ? 32 : 16;
    constexpr int NIT = K_TOT / BK;

    __shared__ float As[2][BK][64];
    __shared__ float Xs[2][BK][64];

    const int tid = threadIdx.x;
    const int lane = tid & 63;
    const int wid = tid >> 6;        // wave id 0..3 (n-slice of 16)
    const int to = lane & 15;        // o-group: 4 rows each
    const int tn = lane >> 4;        // n-group within wave: 4 cols each
    const int m0 = blockIdx.x * 64;
    const int o0 = blockIdx.y * 64;
    const int xoff = wid * 16 + tn * 4;   // n offset within tile
    const int mb = m0 + xoff;             // global column base for this thread

    const float* wA = (MODE == 0) ? gp.wqkT : (MODE == 1) ? gp.wprojT
                    : (MODE == 2) ? gp.wmlp1T : gp.wmlp2T;
    const float* xf = (MODE == 0) ? gp.xT + (size_t)gp.t * NC * NM : gp.xy;
    const unsigned char* xu = (MODE == 1) ? gp.x_one : gp.h1_sp;

    // byte staging regs (FUSED)
    uint2 xb = {0, 0};
    const int xrow = tid >> 3;           // 0..31
    const int xco = (tid & 7) * 8;       // 0..56

    auto stage = [&](int buf, int c0) {
        if constexpr (!FUSED) {
            // A: 16x64 floats = 4 chunks of (4 rows); wave w stages chunk w.
            gl_lds16(wA + (size_t)(c0 + wid * 4 + (lane >> 4)) * LDA + o0 + (lane & 15) * 4,
                     &As[buf][wid * 4][0]);
            gl_lds16(xf + (size_t)(c0 + wid * 4 + (lane >> 4)) * NM + m0 + (lane & 15) * 4,
                     &Xs[buf][wid * 4][0]);
        } else {
            // A: 32x64 floats = 8 chunks; wave w stages chunks 2w, 2w+1.
#pragma unroll
            for (int r = 0; r < 2; ++r)
                gl_lds16(wA + (size_t)(c0 + wid * 8 + r * 4 + (lane >> 4)) * LDA + o0 + (lane & 15) * 4,
                         &As[buf][wid * 8 + r * 4][0]);
            // X bytes -> regs (8 B/thread covers 32x64 tile)
            xb = *(const uint2*)(xu + (size_t)(c0 + xrow) * NM + m0 + xco);
        }
    };

    auto xflush = [&](int buf) {
        if constexpr (FUSED) {
            float* d = &Xs[buf][xrow][xco];
            const unsigned int w0 = xb.x, w1 = xb.y;
            float4 f0, f1;
            f0.x = (float)(unsigned char)(w0);
            f0.y = (float)(unsigned char)(w0 >> 8);
            f0.z = (float)(unsigned char)(w0 >> 16);
            f0.w = (float)(w0 >> 24);
            f1.x = (float)(unsigned char)(w1);
            f1.y = (float)(unsigned char)(w1 >> 8);
            f1.z = (float)(unsigned char)(w1 >> 16);
            f1.w = (float)(w1 >> 24);
            *(float4*)(d) = f0;
            *(float4*)(d + 4) = f1;
        }
    };

    float acc[4][4];
#pragma unroll
    for (int i = 0; i < 4; ++i)
#pragma unroll
        for (int j = 0; j < 4; ++j) acc[i][j] = 0.0f;

    // prologue
    stage(0, 0);
    if constexpr (FUSED) {
        asm volatile("s_waitcnt vmcnt(0)" ::: "memory");
        xflush(0);
    }
    __syncthreads();

#pragma unroll 1
    for (int it = 0; it < NIT; ++it) {
        const int cur = it & 1;
        const bool more = (it + 1 < NIT);
        if (more) stage(cur ^ 1, (it + 1) * BK);

        const float* as = &As[cur][0][0];
        const float* xs = &Xs[cur][0][0];

        float4 af[2], xv[2];
        af[0] = *(const float4*)(as + to * 4);
        xv[0] = *(const float4*)(xs + xoff);
#pragma unroll
        for (int kk = 0; kk < BK; ++kk) {
            const int s = kk & 1;
            if (kk + 1 < BK) {
                af[s ^ 1] = *(const float4*)(as + (kk + 1) * 64 + to * 4);
                xv[s ^ 1] = *(const float4*)(xs + (kk + 1) * 64 + xoff);
            }
            const float a4[4] = {af[s].x, af[s].y, af[s].z, af[s].w};
            const float x4[4] = {xv[s].x, xv[s].y, xv[s].z, xv[s].w};
#pragma unroll
            for (int i = 0; i < 4; ++i)
#pragma unroll
                for (int j = 0; j < 4; ++j) {
                    if (FUSED) acc[i][j] = __fmaf_rn(a4[i], x4[j], acc[i][j]);
                    else       acc[i][j] = __fadd_rn(acc[i][j], __fmul_rn(a4[i], x4[j]));
                }
        }

        if constexpr (FUSED) {
            asm volatile("s_waitcnt vmcnt(0)" ::: "memory");
            if (more) xflush(cur ^ 1);
        }
        __syncthreads();
    }

    // ---- epilogue: BN + LIF, exact reference op order ----
    if constexpr (MODE == 0) {
        const bool isq = (o0 < NC);
        const float* bs = isq ? gp.q_bn_s : gp.k_bn_s;
        const float* bbv = isq ? gp.q_bn_b : gp.k_bn_b;
        float* vb = isq ? gp.v_q : gp.v_k;
        unsigned char* sb = isq ? gp.q_sp : gp.k_sp;
#pragma unroll
        for (int i = 0; i < 4; ++i) {
            const int oo = (o0 + to * 4 + i) & (NC - 1);
            const float sc = bs[oo], bc = bbv[oo];
            float* vr = vb + (size_t)oo * NM + mb;
            float4 vld = gp.t ? *(const float4*)vr : make_float4(0, 0, 0, 0);
            float vv[4] = {vld.x, vld.y, vld.z, vld.w};
            unsigned int pk = 0;
#pragma unroll
            for (int j = 0; j < 4; ++j) {
                const float z = __fadd_rn(__fmul_rn(acc[i][j], sc), bc);
                int sp;
                vv[j] = lif_step(z, vv[j], 1.0f, sp);
                pk |= (unsigned)sp << (j * 8);
            }
            *(float4*)vr = make_float4(vv[0], vv[1], vv[2], vv[3]);
            *(unsigned int*)(sb + (size_t)oo * NM + mb) = pk;
        }
    } else if constexpr (MODE == 2) {
#pragma unroll
        for (int i = 0; i < 4; ++i) {
            const int o = o0 + to * 4 + i;
            const float bi = gp.mlp1_b[o], sc = gp.mlp1_bn_s[o], bc = gp.mlp1_bn_b[o];
            float* vr = gp.v_h1 + (size_t)o * NM + mb;
            float4 vld = gp.t ? *(const float4*)vr : make_float4(0, 0, 0, 0);
            float vv[4] = {vld.x, vld.y, vld.z, vld.w};
            unsigned int pk = 0;
#pragma unroll
            for (int j = 0; j < 4; ++j) {
                const float z = __fadd_rn(__fmul_rn(__fadd_rn(acc[i][j], bi), sc), bc);
                int sp;
                vv[j] = lif_step(z, vv[j], 1.0f, sp);
                pk |= (unsigned)sp << (j * 8);
            }
            *(float4*)vr = make_float4(vv[0], vv[1], vv[2], vv[3]);
            *(unsigned int*)(gp.h1_sp + (size_t)o * NM + mb) = pk;
        }
    } else if constexpr (MODE == 1) {
#pragma unroll
        for (int i = 0; i < 4; ++i) {
            const int o = o0 + to * 4 + i;
            const float bi = gp.proj_b[o], sc = gp.proj_bn_s[o], bc = gp.proj_bn_b[o];
            float* vr = gp.v_y + (size_t)o * NM + mb;
            const float4 vld = gp.t ? *(const float4*)vr : make_float4(0, 0, 0, 0);
            const float4 xv4 = *(const float4*)(gp.xT + ((size_t)gp.t * NC + o) * NM + mb);
            float vv[4] = {vld.x, vld.y, vld.z, vld.w};
            const float xvv[4] = {xv4.x, xv4.y, xv4.z, xv4.w};
            float xyo[4];
#pragma unroll
            for (int j = 0; j < 4; ++j) {
                const float z = __fadd_rn(__fmul_rn(__fadd_rn(acc[i][j], bi), sc), bc);
                int sp;
                vv[j] = lif_step(z, vv[j], 1.0f, sp);
                xyo[j] = __fadd_rn(xvv[j], (float)sp);   // residual x + y (ref rounding)
            }
            *(float4*)vr = make_float4(vv[0], vv[1], vv[2], vv[3]);
            *(float4*)(gp.xy + (size_t)o * NM + mb) = make_float4(xyo[0], xyo[1], xyo[2], xyo[3]);
        }
    } else {  // MODE 3
#pragma unroll
        for (int i = 0; i < 4; ++i) {
            const int o = o0 + to * 4 + i;
            const float bi = gp.mlp2_b[o], sc = gp.mlp2_bn_s[o], bc = gp.mlp2_bn_b[o];
            float* vr = gp.v_h2 + (size_t)o * NM + mb;
            const float4 vld = gp.t ? *(const float4*)vr : make_float4(0, 0, 0, 0);
            const float4 xyv = *(const float4*)(gp.xy + (size_t)o * NM + mb);
            float vv[4] = {vld.x, vld.y, vld.z, vld.w};
            const float xyf[4] = {xyv.x, xyv.y, xyv.z, xyv.w};
#pragma unroll
            for (int j = 0; j < 4; ++j) {
                const float z = __fadd_rn(__fmul_rn(__fadd_rn(acc[i][j], bi), sc), bc);
                int sp;
                vv[j] = lif_step(z, vv[j], 1.0f, sp);
                const int m = mb + j;
                const int b = m / NN;
                const int n = m - b * NN;
                gp.out[(((size_t)gp.t * NB + b) * NC + o) * NN + n] = __fadd_rn(xyf[j], (float)sp);
            }
            *(float4*)vr = make_float4(vv[0], vv[1], vv[2], vv[3]);
        }
    }
}

extern "C" void kernel_launch(void* const* d_in, const int* in_sizes, int n_in,
                              void* d_out, int out_size, void* d_ws, size_t ws_size,
                              hipStream_t stream) {
    const float* x       = (const float*)d_in[0];
    const float* q_w     = (const float*)d_in[1];
    const float* k_w     = (const float*)d_in[4];
    const float* proj_w  = (const float*)d_in[7];
    const float* mlp1_w  = (const float*)d_in[11];
    const float* mlp2_w  = (const float*)d_in[15];

    GP gp;
    gp.q_bn_s = (const float*)d_in[2];  gp.q_bn_b = (const float*)d_in[3];
    gp.k_bn_s = (const float*)d_in[5];  gp.k_bn_b = (const float*)d_in[6];
    gp.proj_b = (const float*)d_in[8];  gp.proj_bn_s = (const float*)d_in[9];  gp.proj_bn_b = (const float*)d_in[10];
    gp.mlp1_b = (const float*)d_in[12]; gp.mlp1_bn_s = (const float*)d_in[13]; gp.mlp1_bn_b = (const float*)d_in[14];
    gp.mlp2_b = (const float*)d_in[16]; gp.mlp2_bn_s = (const float*)d_in[17]; gp.mlp2_bn_b = (const float*)d_in[18];
    gp.out = (float*)d_out;

    char* ws = (char*)d_ws;
    size_t off = 0;
    auto alloc = [&](size_t bytes) -> void* {
        void* r = ws + off;
        off += (bytes + 255) & ~(size_t)255;
        return r;
    };
    float* wqkT   = (float*)alloc((size_t)512 * 1024 * 4);
    float* wprojT = (float*)alloc((size_t)512 * 512 * 4);
    float* wmlp1T = (float*)alloc((size_t)512 * 2048 * 4);
    float* wmlp2T = (float*)alloc((size_t)2048 * 512 * 4);
    float* xT     = (float*)alloc((size_t)NT * NC * NM * 4);
    gp.xy     = (float*)alloc((size_t)NC * NM * 4);
    gp.v_q    = (float*)alloc((size_t)NC * NM * 4);
    gp.v_k    = (float*)alloc((size_t)NC * NM * 4);
    gp.v_y    = (float*)alloc((size_t)NC * NM * 4);
    gp.v_h2   = (float*)alloc((size_t)NC * NM * 4);
    gp.v_h1   = (float*)alloc((size_t)NCH * NM * 4);
    gp.v_attn = (float*)alloc((size_t)NH * NM * 4);
    gp.q_sp   = (unsigned char*)alloc((size_t)NC * NM);
    gp.k_sp   = (unsigned char*)alloc((size_t)NC * NM);
    gp.x_one  = (unsigned char*)alloc((size_t)NC * NM);
    gp.h1_sp  = (unsigned char*)alloc((size_t)NCH * NM);
    gp.attn_sp= (unsigned char*)alloc((size_t)NH * NM);
    gp.wqkT = wqkT; gp.wprojT = wprojT; gp.wmlp1T = wmlp1T; gp.wmlp2T = wmlp2T;
    gp.xT = xT;

    // one-time (per call) layout transforms
    trw_k<<<dim3(16, 16), 256, 0, stream>>>(q_w,    wqkT,   512,  1024, 0);
    trw_k<<<dim3(16, 16), 256, 0, stream>>>(k_w,    wqkT,   512,  1024, 512);
    trw_k<<<dim3(16, 16), 256, 0, stream>>>(proj_w, wprojT, 512,  512,  0);
    trw_k<<<dim3(16, 64), 256, 0, stream>>>(mlp1_w, wmlp1T, 512,  2048, 0);
    trw_k<<<dim3(64, 16), 256, 0, stream>>>(mlp2_w, wmlp2T, 2048, 512,  0);
    permx_k<<<NT * NC * NB, 64, 0, stream>>>(x, xT);

    for (int t = 0; t < NT; ++t) {
        gp.t = t;
        gemm_lif<0><<<dim3(98, 16), 256, 0, stream>>>(gp);  // q,k
        attn_k<<<dim3(25, NH), 256, 0, stream>>>(gp);       // attn LIF
        xone_k<<<dim3(7, NC), 256, 0, stream>>>(gp);        // k_sp & attn_sp
        gemm_lif<1><<<dim3(98, 8), 256, 0, stream>>>(gp);   // proj -> v_y, xy
        gemm_lif<2><<<dim3(98, 32), 256, 0, stream>>>(gp);  // mlp1 -> h1_sp
        gemm_lif<3><<<dim3(98, 8), 256, 0, stream>>>(gp);   // mlp2 -> out
    }
}